// Round 19
// baseline (67.522 us; speedup 1.0000x reference)
//
#include <hip/hip_runtime.h>

// Problem: B=4, C=256, C4=64, N=4096, f32 in/out.
//   Q = Wqk@x; V = Wv@x + b; E = Q^T Q / 8; A = softmax_rows(E); out = V @ A
// Fused: out[c,m] = sum_n (V[c,n]/Z[n]) * exp(E[n,m]),  Z[n] = sum_m exp(E[n,m])
// exp via v_exp_f32: Qt scaled by sqrt(log2e/8). z: no shift (2^12 folded into
// u_kernel). av: SHIFT2=12 via E-MFMA C-init fold. P stays IN REGISTERS
// (E-MFMA D-layout == PV B-frag of mfma_f32_16x16x16f16).
// R14 (kept): FRAG-BLOCKED Qt — contiguous 1-KB wave tile loads.
// R19: z-only change (av byte-identical to R18 best): hoist 64 n (a[4][2])
// per block at UNCHANGED grid 1024/occupancy -> z's Qt stream halves
// (256 MB -> 128 MB of L1 lines). 4 m-quarters -> Zp depth 4.

#define CC 256
#define C4C 64
#define NBATCH 4
#define NN 4096
#define QSCALE 0.42466089f   // sqrt(log2(e)/8)
#define SHIFT2 12.0f

typedef _Float16 f16;
typedef _Float16 half2v __attribute__((ext_vector_type(2)));
typedef _Float16 half4 __attribute__((ext_vector_type(4)));
typedef _Float16 half8 __attribute__((ext_vector_type(8)));
typedef __fp16 fp16x2 __attribute__((ext_vector_type(2)));
typedef float floatx4 __attribute__((ext_vector_type(4)));

static __device__ __forceinline__ half2v pkrtz(float a, float b) {
  fp16x2 r = __builtin_amdgcn_cvt_pkrtz(a, b);
  return __builtin_bit_cast(half2v, r);
}

// Load one 16-n tile's MFMA frag pair: lane l gets {row=l&15, k=8*(l>>4)+j}
#define LOADQ(T, A0, A1)                                                   \
  { const f16* p_ = Qb + (size_t)(T) * 1024 + l * 8;                       \
    A0 = *(const half8*)(p_); A1 = *(const half8*)(p_ + 512); }

// ---------------- QV: Q/V projections via MFMA ----------------
#define XT_PITCH 264
__global__ __launch_bounds__(256) void qv_kernel(
    const float* __restrict__ x, const float* __restrict__ Wqk,
    const float* __restrict__ Wv, const float* __restrict__ bv,
    f16* __restrict__ Qtb, float* __restrict__ V)
{
  __shared__ __align__(16) f16 xt[32][XT_PITCH];
  const int b = blockIdx.y;
  const int n0 = blockIdx.x * 32;
  const int tid = threadIdx.x;

  {
    const int nq = tid & 7;
    const int cb = tid >> 3;
    const int c = cb * 8;
    const float* xp = x + (size_t)b * CC * NN + n0 + nq * 4;
    float4 r[8];
#pragma unroll
    for (int j = 0; j < 8; ++j)
      r[j] = *(const float4*)(xp + (size_t)(c + j) * NN);
#pragma unroll
    for (int s = 0; s < 4; ++s) {
      half8 h;
#pragma unroll
      for (int j = 0; j < 8; ++j) h[j] = (f16)(((const float*)&r[j])[s]);
      *(half8*)(&xt[nq * 4 + s][c]) = h;
    }
  }

  const int w = tid >> 6, l = tid & 63, lr = l & 15, lg = l >> 4;
  const float* Wsrc = (w < 2) ? Wqk : Wv;
  const int ocb = (w & 1) * 32;
  half8 af[2][8];
#pragma unroll
  for (int t = 0; t < 2; ++t) {
    const float* wp = Wsrc + (size_t)(ocb + t * 16 + lr) * CC + 8 * lg;
#pragma unroll
    for (int kk = 0; kk < 8; ++kk) {
      float4 wa = *(const float4*)(wp + kk * 32);
      float4 wb = *(const float4*)(wp + kk * 32 + 4);
      half8 h;
      h[0] = (f16)wa.x; h[1] = (f16)wa.y; h[2] = (f16)wa.z; h[3] = (f16)wa.w;
      h[4] = (f16)wb.x; h[5] = (f16)wb.y; h[6] = (f16)wb.z; h[7] = (f16)wb.w;
      af[t][kk] = h;
    }
  }

  __syncthreads();

  floatx4 acc[2][2] = {{{0.f,0.f,0.f,0.f},{0.f,0.f,0.f,0.f}},
                       {{0.f,0.f,0.f,0.f},{0.f,0.f,0.f,0.f}}};
#pragma unroll
  for (int nt = 0; nt < 2; ++nt) {
#pragma unroll
    for (int kk = 0; kk < 8; ++kk) {
      half8 bf = *(const half8*)(&xt[nt * 16 + lr][kk * 32 + 8 * lg]);
      acc[0][nt] = __builtin_amdgcn_mfma_f32_16x16x32_f16(af[0][kk], bf, acc[0][nt], 0, 0, 0);
      acc[1][nt] = __builtin_amdgcn_mfma_f32_16x16x32_f16(af[1][kk], bf, acc[1][nt], 0, 0, 0);
    }
  }

  if (w < 2) {
#pragma unroll
    for (int t = 0; t < 2; ++t)
#pragma unroll
      for (int nt = 0; nt < 2; ++nt) {
        int T = (n0 >> 4) + nt;
        int kg = 2 * t + (lg >> 1);
        union { f16 h[4]; unsigned long long u; } q4;
#pragma unroll
        for (int i = 0; i < 4; ++i) q4.h[i] = (f16)(acc[t][nt][i] * QSCALE);
        *(unsigned long long*)(Qtb + (size_t)(b * 256 + T) * 1024 + w * 512
                               + (kg * 16 + lr) * 8 + (lg & 1) * 4) = q4.u;
      }
  } else {
#pragma unroll
    for (int t = 0; t < 2; ++t)
#pragma unroll
      for (int nt = 0; nt < 2; ++nt) {
        int n = n0 + nt * 16 + lr;
        int oc = (w - 2) * 32 + t * 16 + 4 * lg;
#pragma unroll
        for (int i = 0; i < 4; ++i)
          V[((size_t)(b * C4C) + oc + i) * NN + n] = acc[t][nt][i] + bv[oc + i];
      }
  }
}

// ---------------- Z pass: 64-n hoisted, grid 1024, Zp depth 4 ----------------
// Zp[mq][b][64n-group] partial over a 1024-m quarter. grid 1024 (XCD-swizzled)
// block 256 (4 waves). Block: 64 n (a[4][2] hoisted) x 1024 m; wave w streams
// 16 m-tiles (2 chunks of 8 preloaded). Stream volume: half of R18's z.
__global__ __launch_bounds__(256) void z_kernel(
    const f16* __restrict__ Qtb, float* __restrict__ Zp)
{
  __shared__ float zl[4][64];
  const int bx = blockIdx.x;
  const int xcd = bx & 7, slot = bx >> 3;       // slot 0..127
  const int b = xcd >> 1;                        // 2 XCDs per batch
  const int wu = ((xcd & 1) << 7) | slot;        // 0..255 per batch
  const int n0t = (wu >> 2) * 4;                 // n-tile base (64 n)
  const int mq = wu & 3;                         // m quarter
  const int tid = threadIdx.x;
  const int w = tid >> 6, l = tid & 63, lr = l & 15, lg = l >> 4;
  const f16* Qb = Qtb + (size_t)b * 256 * 1024;

  half8 a[4][2];
#pragma unroll
  for (int t = 0; t < 4; ++t) LOADQ(n0t + t, a[t][0], a[t][1]);

  const int tstr = mq * 64 + w * 16;             // wave's m-tile base
  float rs[4][4];
#pragma unroll
  for (int t = 0; t < 4; ++t)
#pragma unroll
    for (int i = 0; i < 4; ++i) rs[t][i] = 0.f;

#pragma unroll 1
  for (int ch = 0; ch < 2; ++ch) {
    half8 bb[8][2];
#pragma unroll
    for (int mt = 0; mt < 8; ++mt) {
      const f16* p_ = Qb + (size_t)(tstr + ch * 8 + mt) * 1024 + l * 8;
      bb[mt][0] = *(const half8*)(p_);
      bb[mt][1] = *(const half8*)(p_ + 512);
    }
#pragma unroll
    for (int mt = 0; mt < 8; ++mt) {
#pragma unroll
      for (int t = 0; t < 4; ++t) {
        floatx4 d = {0.f, 0.f, 0.f, 0.f};
        d = __builtin_amdgcn_mfma_f32_16x16x32_f16(a[t][0], bb[mt][0], d, 0, 0, 0);
        d = __builtin_amdgcn_mfma_f32_16x16x32_f16(a[t][1], bb[mt][1], d, 0, 0, 0);
#pragma unroll
        for (int i = 0; i < 4; ++i) rs[t][i] += __builtin_amdgcn_exp2f(d[i]);
      }
    }
  }

#pragma unroll
  for (int t = 0; t < 4; ++t)
#pragma unroll
    for (int i = 0; i < 4; ++i) {
      float v = rs[t][i];
      v += __shfl_xor(v, 1); v += __shfl_xor(v, 2);
      v += __shfl_xor(v, 4); v += __shfl_xor(v, 8);
      rs[t][i] = v;
    }
  if (lr == 0) {
#pragma unroll
    for (int t = 0; t < 4; ++t)
#pragma unroll
      for (int i = 0; i < 4; ++i)
        zl[w][16 * t + 4 * lg + i] = rs[t][i];
  }
  __syncthreads();
  if (tid < 64) {   // fixed-order cross-wave sum: deterministic
    float s = zl[0][tid] + zl[1][tid] + zl[2][tid] + zl[3][tid];
    Zp[(size_t)mq * NBATCH * NN + b * NN + n0t * 16 + tid] = s;
  }
}

// ---------------- Z reduce: Z[i] = sum_{k<4} Zp[k][i] (fixed order) -----------
__global__ __launch_bounds__(256) void zr_kernel(
    const float* __restrict__ Zp, float* __restrict__ Z)
{
  int i = blockIdx.x * 256 + threadIdx.x;   // 4*4096 = 16384
  float s = 0.f;
#pragma unroll
  for (int k = 0; k < 4; ++k) s += Zp[(size_t)k * NBATCH * NN + i];
  Z[i] = s;
}

// ---------------- U: blocked U4[b][n/16][c][16] = V * 2^12 / Zraw (fp16) -------
__global__ __launch_bounds__(256) void u_kernel(
    const float* __restrict__ V, const float* __restrict__ Z,
    f16* __restrict__ U4)
{
  size_t t = (size_t)blockIdx.x * 256 + threadIdx.x;  // 128K threads
  size_t e = t * 8;
  int b = (int)(e >> 18);
  int c = (int)((e >> 12) & 63);
  int n = (int)(e & (NN - 1));
  const float* vp = V + (size_t)b * C4C * NN + (size_t)c * NN + n;
  float4 v0 = *(const float4*)(vp);
  float4 v1 = *(const float4*)(vp + 4);
  const float* zp = Z + b * NN + n;
  float4 z0 = *(const float4*)(zp);
  float4 z1 = *(const float4*)(zp + 4);
  half2v h0 = pkrtz(v0.x * 4096.0f / z0.x, v0.y * 4096.0f / z0.y);
  half2v h1 = pkrtz(v0.z * 4096.0f / z0.z, v0.w * 4096.0f / z0.w);
  half2v h2 = pkrtz(v1.x * 4096.0f / z1.x, v1.y * 4096.0f / z1.y);
  half2v h3 = pkrtz(v1.z * 4096.0f / z1.z, v1.w * 4096.0f / z1.w);
  half8 h = {h0[0], h0[1], h1[0], h1[1], h2[0], h2[1], h3[0], h3[1]};
  *(half8*)(U4 + (size_t)b * (C4C * NN) + (size_t)(n >> 4) * 1024 + c * 16 + (n & 15)) = h;
}

// ---------------- PV pass: 8 waves, m32, blocked loads, unroll 2 (R18) -------
#define LOADU(NB, UA)                                                      \
  { const f16* up_ = Ub + (size_t)(NB) * 1024 + 4 * lg;                    \
    _Pragma("unroll")                                                      \
    for (int cs = 0; cs < 4; ++cs)                                         \
      UA[cs] = *(const half4*)(up_ + (16 * cs + lr) * 16); }

__global__ __launch_bounds__(512, 4) void av_kernel(
    const f16* __restrict__ Qtb, const f16* __restrict__ U4,
    float* __restrict__ Out)
{
  __shared__ float red[8][2][16][17];  // ~17.4 KB

  const int bx = blockIdx.x;
  const int xcd = bx & 7, slot = bx >> 3;          // slot 0..63
  const int b = xcd >> 1;                          // 2 XCDs per batch
  const int m0 = (((xcd & 1) << 6) | slot) * 32;   // 128 m-tiles per batch
  const int tid = threadIdx.x;
  const int w = tid >> 6;                          // 0..7
  const int l = tid & 63;
  const int lr = l & 15, lg = l >> 4;

  const f16* Qb = Qtb + (size_t)b * 256 * 1024;
  const f16* Ub = U4 + (size_t)b * (C4C * NN);

  // hoisted E B-frags for the 32-m tile (tiles m0/16, m0/16+1)
  half8 bq[2][2];
  LOADQ((m0 >> 4), bq[0][0], bq[0][1]);
  LOADQ((m0 >> 4) + 1, bq[1][0], bq[1][1]);

  floatx4 o[4][2];
#pragma unroll
  for (int cs = 0; cs < 4; ++cs)
#pragma unroll
    for (int t = 0; t < 2; ++t) o[cs][t] = (floatx4){0.f, 0.f, 0.f, 0.f};

#pragma unroll 2
  for (int it = 0; it < 32; ++it) {
    const int T = it * 8 + w;                      // this wave's n-tile
    half8 a0, a1;
    LOADQ(T, a0, a1);
    half4 ua[4];
    LOADU(T, ua);

    floatx4 dA = {-SHIFT2, -SHIFT2, -SHIFT2, -SHIFT2};
    floatx4 dB = {-SHIFT2, -SHIFT2, -SHIFT2, -SHIFT2};
    dA = __builtin_amdgcn_mfma_f32_16x16x32_f16(a0, bq[0][0], dA, 0, 0, 0);
    dB = __builtin_amdgcn_mfma_f32_16x16x32_f16(a0, bq[1][0], dB, 0, 0, 0);
    dA = __builtin_amdgcn_mfma_f32_16x16x32_f16(a1, bq[0][1], dA, 0, 0, 0);
    dB = __builtin_amdgcn_mfma_f32_16x16x32_f16(a1, bq[1][1], dB, 0, 0, 0);

    half2v p0a = pkrtz(__builtin_amdgcn_exp2f(dA[0]), __builtin_amdgcn_exp2f(dA[1]));
    half2v p0b = pkrtz(__builtin_amdgcn_exp2f(dA[2]), __builtin_amdgcn_exp2f(dA[3]));
    half2v p1a = pkrtz(__builtin_amdgcn_exp2f(dB[0]), __builtin_amdgcn_exp2f(dB[1]));
    half2v p1b = pkrtz(__builtin_amdgcn_exp2f(dB[2]), __builtin_amdgcn_exp2f(dB[3]));
    half4 bt0 = {p0a[0], p0a[1], p0b[0], p0b[1]};
    half4 bt1 = {p1a[0], p1a[1], p1b[0], p1b[1]};
#pragma unroll
    for (int cs = 0; cs < 4; ++cs) {
      o[cs][0] = __builtin_amdgcn_mfma_f32_16x16x16f16(ua[cs], bt0, o[cs][0], 0, 0, 0);
      o[cs][1] = __builtin_amdgcn_mfma_f32_16x16x16f16(ua[cs], bt1, o[cs][1], 0, 0, 0);
    }
  }

  // ---- 8-wave reduction, fixed order: deterministic, no atomics ----
#pragma unroll 1
  for (int cs = 0; cs < 4; ++cs) {
    __syncthreads();
#pragma unroll
    for (int t = 0; t < 2; ++t)
#pragma unroll
      for (int i = 0; i < 4; ++i)
        red[w][t][4 * lg + i][lr] = o[cs][t][i];
    __syncthreads();
    const int t = tid >> 8;              // 0..1
    const int r = (tid >> 4) & 15;       // 0..15
    const int col = tid & 15;            // 0..15
    float ssum = 0.f;
#pragma unroll
    for (int ww = 0; ww < 8; ++ww) ssum += red[ww][t][r][col];
    Out[((size_t)b * C4C + cs * 16 + r) * NN + m0 + t * 16 + col] = ssum;
  }
}

// ---------------- launch ----------------
// ws layout (~8.06 MB, Zp aliased over U4 region — dead before U4 is written):
//   Qtb f16 [4][256][2][64][8] 2 MiB    @ 0   (frag-blocked)
//   V   f32 [4][64][4096]      4 MiB    @ 2 MiB
//   Z   f32 [4][4096]          64 KiB   @ 6 MiB
//   U4  f16 [4][256][64][16]   2 MiB    @ 6 MiB + 64 KiB
//   Zp  f32 [4][4][4096]       256 KiB  @ 6 MiB + 64 KiB (aliases U4)
extern "C" void kernel_launch(void* const* d_in, const int* in_sizes, int n_in,
                              void* d_out, int out_size, void* d_ws, size_t ws_size,
                              hipStream_t stream)
{
  const float* x   = (const float*)d_in[0];
  const float* Wqk = (const float*)d_in[1];
  const float* Wv  = (const float*)d_in[2];
  const float* bv  = (const float*)d_in[3];
  float* out = (float*)d_out;

  char* ws = (char*)d_ws;
  f16*   Qtb = (f16*)(ws);
  float* V   = (float*)(ws + (2u << 20));
  float* Z   = (float*)(ws + (6u << 20));
  f16*   U4  = (f16*)(ws + (6u << 20) + (64u << 10));
  float* Zp  = (float*)(ws + (6u << 20) + (64u << 10));  // alias: dead before U4

  qv_kernel<<<dim3(128, 4), 256, 0, stream>>>(x, Wqk, Wv, bv, Qtb, V);
  z_kernel<<<dim3(1024), 256, 0, stream>>>(Qtb, Zp);
  zr_kernel<<<dim3(64), 256, 0, stream>>>(Zp, Z);
  u_kernel<<<dim3(512), 256, 0, stream>>>(V, Z, U4);
  av_kernel<<<dim3(512), 512, 0, stream>>>(Qtb, U4, out);
}

// Round 20
// 63.027 us; speedup vs baseline: 1.0713x; 1.0713x over previous
//
#include <hip/hip_runtime.h>

// Problem: B=4, C=256, C4=64, N=4096, f32 in/out.
//   Q = Wqk@x; V = Wv@x + b; E = Q^T Q / 8; A = softmax_rows(E); out = V @ A
// Fused: out[c,m] = sum_n V[c,n] * exp2(dot_nm - 12) * (4096/Zraw[n]),
//        Zraw[n] = sum_m exp2(dot_nm);  dot = log2e*E (Qt scaled).
// R14 (kept): FRAG-BLOCKED Qt — contiguous 1-KB wave tile loads.
// R20: u_kernel DELETED. qv writes V directly in blocked f16 (U4's layout);
// zr emits Zinv = 4096/Z; av folds Zinv into the bt B-frag (4 muls + one
// broadcast float4/tile). 4 dispatches, ws 8.07 -> 4.2 MB. z/av = R18 best.

#define CC 256
#define C4C 64
#define NBATCH 4
#define NN 4096
#define QSCALE 0.42466089f   // sqrt(log2(e)/8)
#define SHIFT2 12.0f

typedef _Float16 f16;
typedef _Float16 half2v __attribute__((ext_vector_type(2)));
typedef _Float16 half4 __attribute__((ext_vector_type(4)));
typedef _Float16 half8 __attribute__((ext_vector_type(8)));
typedef __fp16 fp16x2 __attribute__((ext_vector_type(2)));
typedef float floatx4 __attribute__((ext_vector_type(4)));

static __device__ __forceinline__ half2v pkrtz(float a, float b) {
  fp16x2 r = __builtin_amdgcn_cvt_pkrtz(a, b);
  return __builtin_bit_cast(half2v, r);
}

// Load one 16-n tile's MFMA frag pair: lane l gets {row=l&15, k=8*(l>>4)+j}
#define LOADQ(T, A0, A1)                                                   \
  { const f16* p_ = Qb + (size_t)(T) * 1024 + l * 8;                       \
    A0 = *(const half8*)(p_); A1 = *(const half8*)(p_ + 512); }

// ---------------- QV: Q/V projections via MFMA ----------------
// grid (128, 4) block 256 (4 waves). Block tile: 128 oc x 32 n, K=C=256.
// Q -> frag-blocked Qtb; V -> blocked f16 V4[b][T][c][16] (PV A-frag layout).
#define XT_PITCH 264
__global__ __launch_bounds__(256) void qv_kernel(
    const float* __restrict__ x, const float* __restrict__ Wqk,
    const float* __restrict__ Wv, const float* __restrict__ bv,
    f16* __restrict__ Qtb, f16* __restrict__ V4)
{
  __shared__ __align__(16) f16 xt[32][XT_PITCH];
  const int b = blockIdx.y;
  const int n0 = blockIdx.x * 32;
  const int tid = threadIdx.x;

  {
    const int nq = tid & 7;
    const int cb = tid >> 3;
    const int c = cb * 8;
    const float* xp = x + (size_t)b * CC * NN + n0 + nq * 4;
    float4 r[8];
#pragma unroll
    for (int j = 0; j < 8; ++j)
      r[j] = *(const float4*)(xp + (size_t)(c + j) * NN);
#pragma unroll
    for (int s = 0; s < 4; ++s) {
      half8 h;
#pragma unroll
      for (int j = 0; j < 8; ++j) h[j] = (f16)(((const float*)&r[j])[s]);
      *(half8*)(&xt[nq * 4 + s][c]) = h;
    }
  }

  const int w = tid >> 6, l = tid & 63, lr = l & 15, lg = l >> 4;
  const float* Wsrc = (w < 2) ? Wqk : Wv;
  const int ocb = (w & 1) * 32;
  half8 af[2][8];
#pragma unroll
  for (int t = 0; t < 2; ++t) {
    const float* wp = Wsrc + (size_t)(ocb + t * 16 + lr) * CC + 8 * lg;
#pragma unroll
    for (int kk = 0; kk < 8; ++kk) {
      float4 wa = *(const float4*)(wp + kk * 32);
      float4 wb = *(const float4*)(wp + kk * 32 + 4);
      half8 h;
      h[0] = (f16)wa.x; h[1] = (f16)wa.y; h[2] = (f16)wa.z; h[3] = (f16)wa.w;
      h[4] = (f16)wb.x; h[5] = (f16)wb.y; h[6] = (f16)wb.z; h[7] = (f16)wb.w;
      af[t][kk] = h;
    }
  }

  __syncthreads();

  floatx4 acc[2][2] = {{{0.f,0.f,0.f,0.f},{0.f,0.f,0.f,0.f}},
                       {{0.f,0.f,0.f,0.f},{0.f,0.f,0.f,0.f}}};
#pragma unroll
  for (int nt = 0; nt < 2; ++nt) {
#pragma unroll
    for (int kk = 0; kk < 8; ++kk) {
      half8 bf = *(const half8*)(&xt[nt * 16 + lr][kk * 32 + 8 * lg]);
      acc[0][nt] = __builtin_amdgcn_mfma_f32_16x16x32_f16(af[0][kk], bf, acc[0][nt], 0, 0, 0);
      acc[1][nt] = __builtin_amdgcn_mfma_f32_16x16x32_f16(af[1][kk], bf, acc[1][nt], 0, 0, 0);
    }
  }

  if (w < 2) {
    // Q blocked write: oc = w*32+t*16+4lg+i -> kg=2t+(lg>>1)
#pragma unroll
    for (int t = 0; t < 2; ++t)
#pragma unroll
      for (int nt = 0; nt < 2; ++nt) {
        int T = (n0 >> 4) + nt;
        int kg = 2 * t + (lg >> 1);
        union { f16 h[4]; unsigned long long u; } q4;
#pragma unroll
        for (int i = 0; i < 4; ++i) q4.h[i] = (f16)(acc[t][nt][i] * QSCALE);
        *(unsigned long long*)(Qtb + (size_t)(b * 256 + T) * 1024 + w * 512
                               + (kg * 16 + lr) * 8 + (lg & 1) * 4) = q4.u;
      }
  } else {
    // V blocked f16 write: idx = (b*256+T)*1024 + oc*16 + lr
#pragma unroll
    for (int t = 0; t < 2; ++t)
#pragma unroll
      for (int nt = 0; nt < 2; ++nt) {
        int T = (n0 >> 4) + nt;
        int oc = (w - 2) * 32 + t * 16 + 4 * lg;
#pragma unroll
        for (int i = 0; i < 4; ++i)
          V4[(size_t)(b * 256 + T) * 1024 + (oc + i) * 16 + lr] =
              (f16)(acc[t][nt][i] + bv[oc + i]);
      }
  }
}

// ---------------- Z pass (R18): 2-stage pipeline, blocked Qt loads -----------
#define Z_PRELOAD(TBEG)                                                    \
  { _Pragma("unroll")                                                      \
    for (int mt = 0; mt < 8; ++mt) {                                       \
      const f16* p_ = Qb + (size_t)((TBEG) + mt) * 1024 + l * 8;           \
      bb[mt][0] = *(const half8*)(p_);                                     \
      bb[mt][1] = *(const half8*)(p_ + 512);                               \
    } }

#define Z_E(MT, D0, D1)                                                    \
  { D0 = (floatx4){0.f,0.f,0.f,0.f}; D1 = (floatx4){0.f,0.f,0.f,0.f};      \
    D0 = __builtin_amdgcn_mfma_f32_16x16x32_f16(a[0][0], bb[MT][0], D0, 0, 0, 0); \
    D1 = __builtin_amdgcn_mfma_f32_16x16x32_f16(a[1][0], bb[MT][0], D1, 0, 0, 0); \
    D0 = __builtin_amdgcn_mfma_f32_16x16x32_f16(a[0][1], bb[MT][1], D0, 0, 0, 0); \
    D1 = __builtin_amdgcn_mfma_f32_16x16x32_f16(a[1][1], bb[MT][1], D1, 0, 0, 0); }

#define Z_SM(D0, D1)                                                       \
  { _Pragma("unroll")                                                      \
    for (int i = 0; i < 4; ++i) {                                          \
      rs[0][i] += __builtin_amdgcn_exp2f(D0[i]);                           \
      rs[1][i] += __builtin_amdgcn_exp2f(D1[i]); } }

#define Z_TILES17                                                          \
  Z_E(1, dB0, dB1); Z_SM(dA0, dA1);                                        \
  Z_E(2, dA0, dA1); Z_SM(dB0, dB1);                                        \
  Z_E(3, dB0, dB1); Z_SM(dA0, dA1);                                        \
  Z_E(4, dA0, dA1); Z_SM(dB0, dB1);                                        \
  Z_E(5, dB0, dB1); Z_SM(dA0, dA1);                                        \
  Z_E(6, dA0, dA1); Z_SM(dB0, dB1);                                        \
  Z_E(7, dB0, dB1); Z_SM(dA0, dA1);

__global__ __launch_bounds__(256) void z_kernel(
    const f16* __restrict__ Qtb, float* __restrict__ Zp)
{
  __shared__ float zl[4][32];
  const int bx = blockIdx.x;
  const int xcd = bx & 7, slot = bx >> 3;       // slot 0..127
  const int b = xcd >> 1;                        // 2 XCDs per batch
  const int wu = ((xcd & 1) << 7) | slot;        // 0..255 per batch
  const int n0 = (wu >> 1) * 32;                 // nb 0..127
  const int mh = wu & 1;                         // m half
  const int tid = threadIdx.x;
  const int w = tid >> 6, l = tid & 63, lr = l & 15, lg = l >> 4;
  const f16* Qb = Qtb + (size_t)b * 256 * 1024;

  half8 a[2][2];
  LOADQ((n0 >> 4), a[0][0], a[0][1]);
  LOADQ((n0 >> 4) + 1, a[1][0], a[1][1]);

  const int tstr = mh * 128 + w * 32;            // tile base (512 m = 32 tiles)
  half8 bb[8][2];
  floatx4 dA0, dA1, dB0, dB1;
  float rs[2][4] = {{0.f,0.f,0.f,0.f},{0.f,0.f,0.f,0.f}};

  Z_PRELOAD(tstr);
  Z_E(0, dA0, dA1);
  Z_TILES17;
#pragma unroll 1
  for (int mch = 1; mch < 4; ++mch) {
    Z_PRELOAD(tstr + mch * 8);
    Z_SM(dB0, dB1);
    Z_E(0, dA0, dA1);
    Z_TILES17;
  }
  Z_SM(dB0, dB1);

#pragma unroll
  for (int t = 0; t < 2; ++t)
#pragma unroll
    for (int i = 0; i < 4; ++i) {
      float v = rs[t][i];
      v += __shfl_xor(v, 1); v += __shfl_xor(v, 2);
      v += __shfl_xor(v, 4); v += __shfl_xor(v, 8);
      rs[t][i] = v;
    }
  if (lr == 0) {
#pragma unroll
    for (int t = 0; t < 2; ++t)
#pragma unroll
      for (int i = 0; i < 4; ++i)
        zl[w][16 * t + 4 * lg + i] = rs[t][i];
  }
  __syncthreads();
  if (tid < 32) {   // fixed-order cross-wave sum: deterministic
    float s = zl[0][tid] + zl[1][tid] + zl[2][tid] + zl[3][tid];
    Zp[(size_t)mh * NBATCH * NN + b * NN + n0 + tid] = s;
  }
}

// ---------------- Z reduce -> Zinv = 4096 / (Zp0 + Zp1) ----------------------
__global__ __launch_bounds__(256) void zr_kernel(
    const float* __restrict__ Zp, float* __restrict__ Zinv)
{
  int i = blockIdx.x * 256 + threadIdx.x;   // 4*4096 = 16384
  Zinv[i] = 4096.0f / (Zp[i] + Zp[(size_t)NBATCH * NN + i]);
}

// ---------------- PV pass: R18 best + Zinv fold into bt ----------------------
// grid 512 (XCD-swizzled) block 512 (8 waves, (512,4)). Block: 32 m, all n.
// Wave w: tiles w+8i, i=0..31. Per step: LOADQ + LOADV + zi(float4 bcast) ->
//   E-MFMA x4 (C-init -SHIFT2) -> exp2*zi -> pkrtz -> PV-MFMA x8 (K=16).
// End: fixed-order 8-wave LDS reduction (deterministic), direct stores.
#define LOADV(NB, UA)                                                      \
  { const f16* up_ = Vb + (size_t)(NB) * 1024 + 4 * lg;                    \
    _Pragma("unroll")                                                      \
    for (int cs = 0; cs < 4; ++cs)                                         \
      UA[cs] = *(const half4*)(up_ + (16 * cs + lr) * 16); }

__global__ __launch_bounds__(512, 4) void av_kernel(
    const f16* __restrict__ Qtb, const f16* __restrict__ V4,
    const float* __restrict__ Zinv, float* __restrict__ Out)
{
  __shared__ float red[8][2][16][17];  // ~17.4 KB

  const int bx = blockIdx.x;
  const int xcd = bx & 7, slot = bx >> 3;          // slot 0..63
  const int b = xcd >> 1;                          // 2 XCDs per batch
  const int m0 = (((xcd & 1) << 6) | slot) * 32;   // 128 m-tiles per batch
  const int tid = threadIdx.x;
  const int w = tid >> 6;                          // 0..7
  const int l = tid & 63;
  const int lr = l & 15, lg = l >> 4;

  const f16* Qb = Qtb + (size_t)b * 256 * 1024;
  const f16* Vb = V4 + (size_t)b * 256 * 1024;
  const float* Zb = Zinv + b * NN;

  // hoisted E B-frags for the 32-m tile (tiles m0/16, m0/16+1)
  half8 bq[2][2];
  LOADQ((m0 >> 4), bq[0][0], bq[0][1]);
  LOADQ((m0 >> 4) + 1, bq[1][0], bq[1][1]);

  floatx4 o[4][2];
#pragma unroll
  for (int cs = 0; cs < 4; ++cs)
#pragma unroll
    for (int t = 0; t < 2; ++t) o[cs][t] = (floatx4){0.f, 0.f, 0.f, 0.f};

#pragma unroll 2
  for (int it = 0; it < 32; ++it) {
    const int T = it * 8 + w;                      // this wave's n-tile
    half8 a0, a1;
    LOADQ(T, a0, a1);
    half4 va[4];
    LOADV(T, va);
    const float4 zi = *(const float4*)(Zb + T * 16 + 4 * lg);

    floatx4 dA = {-SHIFT2, -SHIFT2, -SHIFT2, -SHIFT2};
    floatx4 dB = {-SHIFT2, -SHIFT2, -SHIFT2, -SHIFT2};
    dA = __builtin_amdgcn_mfma_f32_16x16x32_f16(a0, bq[0][0], dA, 0, 0, 0);
    dB = __builtin_amdgcn_mfma_f32_16x16x32_f16(a0, bq[1][0], dB, 0, 0, 0);
    dA = __builtin_amdgcn_mfma_f32_16x16x32_f16(a1, bq[0][1], dA, 0, 0, 0);
    dB = __builtin_amdgcn_mfma_f32_16x16x32_f16(a1, bq[1][1], dB, 0, 0, 0);

    half2v p0a = pkrtz(__builtin_amdgcn_exp2f(dA[0]) * zi.x,
                       __builtin_amdgcn_exp2f(dA[1]) * zi.y);
    half2v p0b = pkrtz(__builtin_amdgcn_exp2f(dA[2]) * zi.z,
                       __builtin_amdgcn_exp2f(dA[3]) * zi.w);
    half2v p1a = pkrtz(__builtin_amdgcn_exp2f(dB[0]) * zi.x,
                       __builtin_amdgcn_exp2f(dB[1]) * zi.y);
    half2v p1b = pkrtz(__builtin_amdgcn_exp2f(dB[2]) * zi.z,
                       __builtin_amdgcn_exp2f(dB[3]) * zi.w);
    half4 bt0 = {p0a[0], p0a[1], p0b[0], p0b[1]};
    half4 bt1 = {p1a[0], p1a[1], p1b[0], p1b[1]};
#pragma unroll
    for (int cs = 0; cs < 4; ++cs) {
      o[cs][0] = __builtin_amdgcn_mfma_f32_16x16x16f16(va[cs], bt0, o[cs][0], 0, 0, 0);
      o[cs][1] = __builtin_amdgcn_mfma_f32_16x16x16f16(va[cs], bt1, o[cs][1], 0, 0, 0);
    }
  }

  // ---- 8-wave reduction, fixed order: deterministic, no atomics ----
#pragma unroll 1
  for (int cs = 0; cs < 4; ++cs) {
    __syncthreads();
#pragma unroll
    for (int t = 0; t < 2; ++t)
#pragma unroll
      for (int i = 0; i < 4; ++i)
        red[w][t][4 * lg + i][lr] = o[cs][t][i];
    __syncthreads();
    const int t = tid >> 8;              // 0..1
    const int r = (tid >> 4) & 15;       // 0..15
    const int col = tid & 15;            // 0..15
    float ssum = 0.f;
#pragma unroll
    for (int ww = 0; ww < 8; ++ww) ssum += red[ww][t][r][col];
    Out[((size_t)b * C4C + cs * 16 + r) * NN + m0 + t * 16 + col] = ssum;
  }
}

// ---------------- launch ----------------
// ws layout (4.2 MB, no aliasing):
//   Qtb  f16 [4][256][2][64][8] 2 MiB    @ 0        (frag-blocked Q)
//   V4   f16 [4][256][64][16]   2 MiB    @ 2 MiB    (blocked V, PV A-frag)
//   Zp   f32 [2][4][4096]       128 KiB  @ 4 MiB
//   Zinv f32 [4][4096]          64 KiB   @ 4 MiB + 128 KiB
extern "C" void kernel_launch(void* const* d_in, const int* in_sizes, int n_in,
                              void* d_out, int out_size, void* d_ws, size_t ws_size,
                              hipStream_t stream)
{
  const float* x   = (const float*)d_in[0];
  const float* Wqk = (const float*)d_in[1];
  const float* Wv  = (const float*)d_in[2];
  const float* bv  = (const float*)d_in[3];
  float* out = (float*)d_out;

  char* ws = (char*)d_ws;
  f16*   Qtb  = (f16*)(ws);
  f16*   V4   = (f16*)(ws + (2u << 20));
  float* Zp   = (float*)(ws + (4u << 20));
  float* Zinv = (float*)(ws + (4u << 20) + (128u << 10));

  qv_kernel<<<dim3(128, 4), 256, 0, stream>>>(x, Wqk, Wv, bv, Qtb, V4);
  z_kernel<<<dim3(1024), 256, 0, stream>>>(Qtb, Zp);
  zr_kernel<<<dim3(64), 256, 0, stream>>>(Zp, Zinv);
  av_kernel<<<dim3(512), 512, 0, stream>>>(Qtb, V4, Zinv, out);
}